// Round 8
// baseline (312.823 us; speedup 1.0000x reference)
//
#include <hip/hip_runtime.h>
#include <cstdint>
#include <cstddef>

#define BM 64
#define THREADS 512
#define A_SLAB 32768                  // 64 rows x 512B (bf16 [64][256])
#define NT 24

typedef __attribute__((ext_vector_type(4))) float f32x4;
typedef __attribute__((ext_vector_type(8))) short bf16x8;
typedef __attribute__((ext_vector_type(2))) unsigned int u32x2;

__device__ __forceinline__ unsigned int f2bf(float f) {
  union { float f; uint32_t u; } v; v.f = f;
  uint32_t r = v.u + 0x7FFFu + ((v.u >> 16) & 1u);   // RNE
  return r >> 16;
}

// WtS: per K-step kt (24 x 32k), 1024 16B-chunks, chunk c =
// [colgroup=c>>6][k8=(c>>4)&3][col=c&15] holding bf16
// W[kt*32+k8*8 .. +7][colgroup*16+col]. GEMM reads fragments straight from
// this L2-resident buffer: lane-consecutive 16B -> contiguous 1KB per inst.
__global__ void wt_kernel(const float* __restrict__ W, unsigned short* __restrict__ WtS) {
  const int gid = blockIdx.x * 256 + threadIdx.x;   // 0..24575
  const int kt = gid >> 10;
  const int c  = gid & 1023;
  const int n  = ((c >> 6) << 4) | (c & 15);
  const int k0 = kt * 32 + ((c >> 4) & 3) * 8;
  unsigned int p[4];
#pragma unroll
  for (int i = 0; i < 4; ++i)
    p[i] = f2bf(W[(size_t)(k0 + 2 * i) * 256 + n]) |
           (f2bf(W[(size_t)(k0 + 2 * i + 1) * 256 + n]) << 16);
  *(u32x2*)((char*)WtS + (size_t)gid * 16)     = u32x2{p[0], p[1]};
  *(u32x2*)((char*)WtS + (size_t)gid * 16 + 8) = u32x2{p[2], p[3]};
}

// 8 waves (2 row x 4 col groups), wave tile 32x64, acc = 32 AGPR.
// 3 supersteps (dest | src | ea+u): stage 64x256-f32 slab as 8x 1KB fully
// CONTIGUOUS loads per wave, hold in regs through 8 substeps, write late.
__global__ __launch_bounds__(THREADS, 4) void edge_gemm(
    const float* __restrict__ srcf, const float* __restrict__ destf,
    const float* __restrict__ eaf, const float* __restrict__ uf,
    const int* __restrict__ batch, const unsigned short* __restrict__ WtS,
    const float* __restrict__ bias, float* __restrict__ out)
{
  __shared__ char smem[2 * A_SLAB];   // 64 KB -> 2 blocks/CU
  const int tid  = threadIdx.x;
  const int lane = tid & 63;
  const int w    = tid >> 6;
  const int wr   = w >> 2;      // 0..1 row-group (32 rows)
  const int wc   = w & 3;       // 0..3 col-group (64 cols)
  const int m0   = blockIdx.x * BM;
  const int l15  = lane & 15;
  const int l4   = lane >> 4;
  const int sw8  = w * 8;       // this wave stages rows sw8..sw8+7

  // u-gather indices for superstep 2 (rows sw8+2i+(lane>>5))
  int ubi[4];
#pragma unroll
  for (int i = 0; i < 4; ++i) ubi[i] = batch[m0 + sw8 + 2 * i + (lane >> 5)];

  float bs[4];
#pragma unroll
  for (int nf = 0; nf < 4; ++nf) bs[nf] = bias[wc * 64 + nf * 16 + l15];

  f32x4 acc[2][4];
  f32x4 z = {0.f, 0.f, 0.f, 0.f};
#pragma unroll
  for (int i = 0; i < 2; ++i)
#pragma unroll
    for (int j = 0; j < 4; ++j) acc[i][j] = z;

  f32x4 sv[8];   // staged slab (all indices static after unroll)

  auto issue_stage = [&](int ss) {
    if (ss < 2) {
      const float* base = (ss == 0) ? destf : srcf;
#pragma unroll
      for (int i = 0; i < 8; ++i)   // one full 1KB row per instruction
        sv[i] = *(const f32x4*)(base + (size_t)(m0 + sw8 + i) * 256 + lane * 4);
    } else {
#pragma unroll
      for (int i = 0; i < 4; ++i)   // ea: 2 rows x 512B per instruction
        sv[i] = *(const f32x4*)(eaf + (size_t)(m0 + sw8 + 2 * i + (lane >> 5)) * 128
                                + (lane & 31) * 4);
#pragma unroll
      for (int i = 0; i < 4; ++i)   // u[batch]: 2 gathered 512B rows per inst
        sv[4 + i] = *(const f32x4*)(uf + (size_t)ubi[i] * 128 + (lane & 31) * 4);
    }
  };

  auto cvt4 = [&](f32x4 v) -> u32x2 {
    u32x2 p;
    p[0] = f2bf(v[0]) | (f2bf(v[1]) << 16);
    p[1] = f2bf(v[2]) | (f2bf(v[3]) << 16);
    return p;
  };

  // LDS slab: [row][512B], 16B-chunk XOR swizzle c ^= (row&7)
  auto write_slab = [&](int buf, int ss) {
    char* Ab = smem + buf * A_SLAB;
    if (ss < 2) {
#pragma unroll
      for (int i = 0; i < 8; ++i) {
        const int r = sw8 + i, c = lane >> 1;
        *(u32x2*)(Ab + r * 512 + (((c ^ (r & 7)) << 4) | ((lane & 1) << 3))) = cvt4(sv[i]);
      }
    } else {
#pragma unroll
      for (int i = 0; i < 4; ++i) {   // ea -> chunks 0..15
        const int r = sw8 + 2 * i + (lane >> 5), c = (lane & 31) >> 1;
        *(u32x2*)(Ab + r * 512 + (((c ^ (r & 7)) << 4) | ((lane & 1) << 3))) = cvt4(sv[i]);
      }
#pragma unroll
      for (int i = 0; i < 4; ++i) {   // u -> chunks 16..31
        const int r = sw8 + 2 * i + (lane >> 5), c = 16 + ((lane & 31) >> 1);
        *(u32x2*)(Ab + r * 512 + (((c ^ (r & 7)) << 4) | ((lane & 1) << 3))) = cvt4(sv[4 + i]);
      }
    }
  };

  auto compute = [&](int buf, int kt) {   // kt = ss*8 + s
    const char* Ab = smem + buf * A_SLAB;
    const char* wb = (const char*)WtS + (size_t)kt * 16384;
    bf16x8 bfr[4], af[2];
#pragma unroll
    for (int nf = 0; nf < 4; ++nf)   // contiguous 1KB per inst from L2
      bfr[nf] = *(const bf16x8*)(wb + (size_t)(((wc * 4 + nf) * 64 + l4 * 16 + l15)) * 16);
    const int s = kt & 7;
#pragma unroll
    for (int mf = 0; mf < 2; ++mf) {
      const int r = wr * 32 + mf * 16 + l15;
      const int c = s * 4 + l4;
      af[mf] = *(const bf16x8*)(Ab + r * 512 + ((c ^ (r & 7)) << 4));
    }
#pragma unroll
    for (int mf = 0; mf < 2; ++mf)
#pragma unroll
      for (int nf = 0; nf < 4; ++nf)
        acc[mf][nf] = __builtin_amdgcn_mfma_f32_16x16x32_bf16(
            af[mf], bfr[nf], acc[mf][nf], 0, 0, 0);
  };

  // ---- prologue ----
  issue_stage(0);
  write_slab(0, 0);       // compiler-counted vmcnt on sv; one cold stall/gen
  __syncthreads();

  // ---- 3 supersteps x 8 substeps; only 3 barriers per generation ----
#pragma unroll
  for (int ss = 0; ss < 3; ++ss) {
    if (ss < 2) issue_stage(ss + 1);        // HBM loads hidden under 8 substeps
#pragma unroll
    for (int s = 0; s < 8; ++s) compute(ss & 1, ss * 8 + s);
    if (ss < 2) {
      write_slab((ss + 1) & 1, ss + 1);     // write-late into other buffer
      __syncthreads();
    }
  }

  // ---- epilogue: bias + ReLU; C/D layout col=lane&15, row=(lane>>4)*4+j ----
#pragma unroll
  for (int mf = 0; mf < 2; ++mf) {
    const int r0 = m0 + wr * 32 + mf * 16 + l4 * 4;
#pragma unroll
    for (int nf = 0; nf < 4; ++nf) {
      const int cn = wc * 64 + nf * 16 + l15;
      const f32x4 v = acc[mf][nf];
#pragma unroll
      for (int j = 0; j < 4; ++j) {
        const float x = v[j] + bs[nf];
        out[(size_t)(r0 + j) * 256 + cn] = x > 0.f ? x : 0.f;
      }
    }
  }
}

extern "C" void kernel_launch(void* const* d_in, const int* in_sizes, int n_in,
                              void* d_out, int out_size, void* d_ws, size_t ws_size,
                              hipStream_t stream) {
  const float* srcf  = (const float*)d_in[0];
  const float* destf = (const float*)d_in[1];
  const float* eaf   = (const float*)d_in[2];
  const float* uf    = (const float*)d_in[3];
  const int*   batch = (const int*)d_in[4];
  const float* W     = (const float*)d_in[5];
  const float* bias  = (const float*)d_in[6];
  float* out = (float*)d_out;
  unsigned short* WtS = (unsigned short*)d_ws;   // 24*16KB = 384 KB

  wt_kernel<<<96, 256, 0, stream>>>(W, WtS);

  edge_gemm<<<320000 / BM, THREADS, 0, stream>>>(
      srcf, destf, eaf, uf, batch, WtS, bias, out);
}

// Round 9
// 302.714 us; speedup vs baseline: 1.0334x; 1.0334x over previous
//
#include <hip/hip_runtime.h>
#include <cstdint>
#include <cstddef>

#define BM 64
#define BN 256
#define BK 32
#define NT 24                         // K-steps
#define THREADS 512
#define A_BYTES (BM * BK * 2)         // 4096
#define B_BYTES (BN * BK * 2)         // 16384
#define BUF_BYTES (A_BYTES + B_BYTES) // 20480
#define NBUF 2                        // 40 KB LDS -> 3 blocks/CU at 84 regs

typedef __attribute__((ext_vector_type(4))) float f32x4;
typedef __attribute__((ext_vector_type(8))) short bf16x8;
typedef __attribute__((ext_vector_type(2))) unsigned int u32x2;

__device__ __forceinline__ unsigned int f2bf(float f) {
  union { float f; uint32_t u; } v; v.f = f;
  uint32_t r = v.u + 0x7FFFu + ((v.u >> 16) & 1u);   // RNE
  return r >> 16;
}

// WtS: per K-step kt (24 x 32k), 1024 16B-chunks, chunk c =
// [colgroup=c>>6][k8=(c>>4)&3][col=c&15] holding bf16
// W[kt*32+k8*8 .. +7][colgroup*16+col]. Identity order for glds + ds_read.
__global__ void wt_kernel(const float* __restrict__ W, unsigned short* __restrict__ WtS) {
  const int gid = blockIdx.x * 256 + threadIdx.x;   // 0..24575
  const int kt = gid >> 10;
  const int c  = gid & 1023;
  const int n  = ((c >> 6) << 4) | (c & 15);
  const int k0 = kt * 32 + ((c >> 4) & 3) * 8;
  unsigned int p[4];
#pragma unroll
  for (int i = 0; i < 4; ++i)
    p[i] = f2bf(W[(size_t)(k0 + 2 * i) * 256 + n]) |
           (f2bf(W[(size_t)(k0 + 2 * i + 1) * 256 + n]) << 16);
  *(u32x2*)((char*)WtS + (size_t)gid * 16)     = u32x2{p[0], p[1]};
  *(u32x2*)((char*)WtS + (size_t)gid * 16 + 8) = u32x2{p[2], p[3]};
}

// 8 waves (2 row-groups x 4 col-groups), wave tile 32x64 -> acc = 32 AGPR,
// total ~84 regs/lane -> 6 waves/SIMD. LDS 40 KB -> 3 blocks/CU = 24 waves/CU:
// three independent barrier groups fill each other's per-step drain windows.
__global__ __launch_bounds__(THREADS, 6) void edge_gemm(
    const float* __restrict__ srcf, const float* __restrict__ destf,
    const float* __restrict__ eaf, const float* __restrict__ uf,
    const int* __restrict__ batch, const unsigned short* __restrict__ WtS,
    const float* __restrict__ bias, float* __restrict__ out)
{
  __shared__ char smem[NBUF * BUF_BYTES];
  const int tid  = threadIdx.x;
  const int lane = tid & 63;
  const int w    = tid >> 6;
  const int wr   = w >> 2;      // 0..1 row-group (32 rows)
  const int wc   = w & 3;       // 0..3 col-group (64 cols)
  const int m0   = blockIdx.x * BM;
  const int l15  = lane & 15;
  const int l4   = lane >> 4;

  // A staging: thread tid owns 8B half-chunk -> LDS addr = tid*8 (linear,
  // conflict-free). chunk ci = tid>>1 = [rg:2][k8:2][r15:4]; half = tid&1.
  const int s_row  = ((tid >> 7) << 4) | ((tid >> 1) & 15);      // rg*16 + r15
  const int s_coff = (((tid >> 5) & 3) << 3) | ((tid & 1) << 2); // k8*8+half*4
  const int s_ae   = m0 + s_row;
  const int s_ub   = batch[s_ae];

  float bs[4];
#pragma unroll
  for (int nf = 0; nf < 4; ++nf) bs[nf] = bias[wc * 64 + nf * 16 + l15];

  f32x4 acc[2][4];
  f32x4 z = {0.f, 0.f, 0.f, 0.f};
#pragma unroll
  for (int i = 0; i < 2; ++i)
#pragma unroll
    for (int j = 0; j < 4; ++j) acc[i][j] = z;

  // concat = [dest(0..7), src(8..15), edge_attr(16..19), u[batch](20..23)]
  auto a_ptr = [&](int kt) -> const float* {
    if (kt < 8)  return destf + (size_t)s_ae * 256 + kt * 32 + s_coff;
    if (kt < 16) return srcf  + (size_t)s_ae * 256 + (kt - 8) * 32 + s_coff;
    if (kt < 20) return eaf   + (size_t)s_ae * 128 + (kt - 16) * 32 + s_coff;
    return uf + (size_t)s_ub * 128 + (kt - 20) * 32 + s_coff;
  };

  f32x4 va;

  // issue 3 vmem ops: 2 glds (B -> buf[kt&1]) + 1 reg load (A)
  auto stage = [&](int kt) {
    char* Bb = smem + (kt & 1) * BUF_BYTES + A_BYTES;
    const char* wb = (const char*)WtS + (size_t)kt * B_BYTES;
#pragma unroll
    for (int j = 0; j < 2; ++j) {
      const char* g = wb + (size_t)(j * 512 + tid) * 16;
      char* l = Bb + (size_t)(j * 512 + w * 64) * 16;   // wave-uniform base
      __builtin_amdgcn_global_load_lds(
          (const __attribute__((address_space(1))) uint32_t*)g,
          (__attribute__((address_space(3))) uint32_t*)l, 16, 0, 0);
    }
    va = *(const f32x4*)a_ptr(kt);
  };
  auto write_a = [&](int kt) {   // cvt + linear ds_write_b64 at tid*8
    char* Ab = smem + (kt & 1) * BUF_BYTES;
    u32x2 p;
    p[0] = f2bf(va[0]) | (f2bf(va[1]) << 16);
    p[1] = f2bf(va[2]) | (f2bf(va[3]) << 16);
    *(u32x2*)(Ab + tid * 8) = p;
  };
  auto compute = [&](int kt) {
    const char* Ab = smem + (kt & 1) * BUF_BYTES;
    const char* Bb = Ab + A_BYTES;
    bf16x8 af[2], bfr[4];
#pragma unroll
    for (int mf = 0; mf < 2; ++mf)   // contiguous 1KiB per wave: conflict-free
      af[mf] = *(const bf16x8*)(Ab + (((wr * 2 + mf) * 64) + l4 * 16 + l15) * 16);
#pragma unroll
    for (int nf = 0; nf < 4; ++nf)
      bfr[nf] = *(const bf16x8*)(Bb + (((wc * 4 + nf) * 64) + l4 * 16 + l15) * 16);
#pragma unroll
    for (int mf = 0; mf < 2; ++mf)
#pragma unroll
      for (int nf = 0; nf < 4; ++nf)
        acc[mf][nf] = __builtin_amdgcn_mfma_f32_16x16x32_bf16(
            af[mf], bfr[nf], acc[mf][nf], 0, 0, 0);
  };

  // ---- prologue ----
  stage(0);
  write_a(0);
  __syncthreads();

  // ---- main loop: double-buffer, distance-1 prefetch ----
#pragma unroll
  for (int kt = 0; kt < NT; ++kt) {
    if (kt + 1 < NT) stage(kt + 1);     // glds + A-load into buf[(kt+1)&1]
    compute(kt);                        // reads buf[kt&1]
    if (kt + 1 < NT) write_a(kt + 1);   // cvt + ds_write into buf[(kt+1)&1]
    __syncthreads();
  }

  // ---- epilogue: bias + ReLU; C/D layout col=lane&15, row=(lane>>4)*4+j ----
#pragma unroll
  for (int mf = 0; mf < 2; ++mf) {
    const int r0 = m0 + wr * 32 + mf * 16 + l4 * 4;
#pragma unroll
    for (int nf = 0; nf < 4; ++nf) {
      const int cn = wc * 64 + nf * 16 + l15;
      const f32x4 v = acc[mf][nf];
#pragma unroll
      for (int j = 0; j < 4; ++j) {
        const float x = v[j] + bs[nf];
        out[(size_t)(r0 + j) * 256 + cn] = x > 0.f ? x : 0.f;
      }
    }
  }
}

extern "C" void kernel_launch(void* const* d_in, const int* in_sizes, int n_in,
                              void* d_out, int out_size, void* d_ws, size_t ws_size,
                              hipStream_t stream) {
  const float* srcf  = (const float*)d_in[0];
  const float* destf = (const float*)d_in[1];
  const float* eaf   = (const float*)d_in[2];
  const float* uf    = (const float*)d_in[3];
  const int*   batch = (const int*)d_in[4];
  const float* W     = (const float*)d_in[5];
  const float* bias  = (const float*)d_in[6];
  float* out = (float*)d_out;
  unsigned short* WtS = (unsigned short*)d_ws;   // 24*16KB = 384 KB

  wt_kernel<<<96, 256, 0, stream>>>(W, WtS);

  edge_gemm<<<320000 / BM, THREADS, 0, stream>>>(
      srcf, destf, eaf, uf, batch, WtS, bias, out);
}